// Round 8
// baseline (53.323 us; speedup 1.0000x reference)
//
#include <hip/hip_runtime.h>
#include <math.h>

// Chamfer loss, B=8, C=3, M=N=4096, fp32 — MFMA, barrier-free main kernel.
//
// sq[m][n] = s2[m] + d2[n] - 2 s.d as a K=16 bf16 GEMM with hi/lo split:
//   A_m = [-2xh,-2xh,-2xl,-2xl | y.. | z.. | s2h,s2l,1,1]   (query rows)
//   B_n = [ xh,  xl,  xh,  xl  | y.. | z.. | 1,1,d2h,d2l]   (reference cols)
// One v_mfma_f32_32x32x16_bf16 per 32x32 tile -> sq in the accumulator.
//
// Round-8 structure (hypothesis test: additive-overhead vs measurement floor):
//   pre    : build augmented A-form AND B-form for BOTH clouds into ws (4 MB).
//   main   : 4096 blocks x 4 waves; each wave owns 32 rows x 512 cols of one
//            direction. B-fragments are read STRAIGHT FROM GLOBAL (L2-resident
//            panels, 1 KB/tile/wave) -> no LDS staging, no __syncthreads,
//            pure {global_load_dwordx4, MFMA, 8 v_min3} stream; row-min
//            finished in-wave by butterfly; partials plain-stored.
//   reduce : min over 8 col-splits, sqrt, mean, 3 atomicAdds.
//
// C layout (m74/m101): col = lane&31, row = (reg&3) + 8*(reg>>2) + 4*(lane>>5)
// A frag: row = lane&31, k = (lane>>5)*8 + j ; B frag: col = lane&31, same k.

constexpr int B = 8;
constexpr int M = 4096;   // == N

typedef __attribute__((ext_vector_type(8)))  short bf16x8;
typedef __attribute__((ext_vector_type(16))) float f32x16;

__device__ inline unsigned short bf16_of(float x) {   // round-to-nearest-even
    unsigned int u = __float_as_uint(x);
    u += 0x7FFFu + ((u >> 16) & 1u);
    return (unsigned short)(u >> 16);
}
__device__ inline float bf16_to_f(unsigned short h) {
    return __uint_as_float(((unsigned int)h) << 16);
}

// ws: Aaug [2 clouds*B][2 hf][M][8]us @ 0    (2 MB)
//     Baug [2 clouds*B][2 hf][M][8]us @ 2 MB (2 MB)
//     part [8 ns][16 db][M] f32      @ 4 MB  (2 MB)

__global__ __launch_bounds__(256) void chamfer_pre(
    const float* __restrict__ src, const float* __restrict__ dst,
    unsigned short* __restrict__ Aaug, unsigned short* __restrict__ Baug)
{
    int idx = blockIdx.x * 256 + threadIdx.x;          // [0, 2*B*M)
    const int i = idx & (M - 1); idx >>= 12;
    const int b = idx & (B - 1); idx >>= 3;
    const int c = idx;                                 // cloud: 0=src, 1=dst

    const float* in = c ? dst : src;
    const float x = in[((size_t)b * 3 + 0) * M + i];
    const float y = in[((size_t)b * 3 + 1) * M + i];
    const float z = in[((size_t)b * 3 + 2) * M + i];
    const float s2 = x * x + y * y + z * z;

    const unsigned short xh = bf16_of(x); const float xhf = bf16_to_f(xh);
    const unsigned short yh = bf16_of(y); const float yhf = bf16_to_f(yh);
    const unsigned short zh = bf16_of(z); const float zhf = bf16_to_f(zh);
    const unsigned short xl = bf16_of(x - xhf);
    const unsigned short yl = bf16_of(y - yhf);
    const unsigned short zl = bf16_of(z - zhf);
    const unsigned short s2h = bf16_of(s2);
    const unsigned short s2l = bf16_of(s2 - bf16_to_f(s2h));
    // -2*hi exact (pow2 scale of a bf16 value)
    const unsigned short nxh = bf16_of(-2.0f * xhf), nxl = bf16_of(-2.0f * (x - xhf));
    const unsigned short nyh = bf16_of(-2.0f * yhf), nyl = bf16_of(-2.0f * (y - yhf));
    const unsigned short nzh = bf16_of(-2.0f * zhf), nzl = bf16_of(-2.0f * (z - zhf));
    const unsigned short one = 0x3F80;

    bf16x8 alo, ahi, blo, bhi;
    alo[0]=(short)nxh; alo[1]=(short)nxh; alo[2]=(short)nxl; alo[3]=(short)nxl;
    alo[4]=(short)nyh; alo[5]=(short)nyh; alo[6]=(short)nyl; alo[7]=(short)nyl;
    ahi[0]=(short)nzh; ahi[1]=(short)nzh; ahi[2]=(short)nzl; ahi[3]=(short)nzl;
    ahi[4]=(short)s2h; ahi[5]=(short)s2l; ahi[6]=(short)one; ahi[7]=(short)one;
    blo[0]=(short)xh; blo[1]=(short)xl; blo[2]=(short)xh; blo[3]=(short)xl;
    blo[4]=(short)yh; blo[5]=(short)yl; blo[6]=(short)yh; blo[7]=(short)yl;
    bhi[0]=(short)zh; bhi[1]=(short)zl; bhi[2]=(short)zh; bhi[3]=(short)zl;
    bhi[4]=(short)one; bhi[5]=(short)one; bhi[6]=(short)s2h; bhi[7]=(short)s2l;  // d2 == s2 of this point

    const size_t base = ((size_t)(c * B + b) * 2) * M;
    *reinterpret_cast<bf16x8*>(&Aaug[(base + i) * 8])     = alo;
    *reinterpret_cast<bf16x8*>(&Aaug[(base + M + i) * 8]) = ahi;
    *reinterpret_cast<bf16x8*>(&Baug[(base + i) * 8])     = blo;
    *reinterpret_cast<bf16x8*>(&Baug[(base + M + i) * 8]) = bhi;
}

// grid 4096 = (dir<<11 | b<<8 | mt<<3 | ns); 256 thr = 4 waves;
// wave w owns rows mt*128 + w*32 .. +32, cols ns*512 .. +512 (16 tiles)
__global__ __launch_bounds__(256) void chamfer_main(
    const unsigned short* __restrict__ Aaug,
    const unsigned short* __restrict__ Baug,
    float* __restrict__ part)     // [8][16][M]
{
    int bid = blockIdx.x;
    const int ns  = bid & 7;  bid >>= 3;
    const int mt  = bid & 31; bid >>= 5;
    const int b   = bid & 7;  bid >>= 3;
    const int dir = bid;
    const int ac = dir;        // rows come from cloud 'dir' (0:src rows)
    const int bc = dir ^ 1;    // cols scan the other cloud

    const int tid  = threadIdx.x;
    const int wave = tid >> 6;
    const int l31  = tid & 31;
    const int hf   = (tid >> 5) & 1;

    const int mrow = mt * 128 + wave * 32 + l31;
    const bf16x8 afrag = *reinterpret_cast<const bf16x8*>(
        &Aaug[(((size_t)(ac * B + b) * 2 + hf) * M + mrow) * 8]);
    const unsigned short* bbase =
        &Baug[(((size_t)(bc * B + b) * 2 + hf) * M + ns * 512 + l31) * 8];

    f32x16 fwd;
#pragma unroll
    for (int r = 0; r < 16; ++r) fwd[r] = 3.0e38f;
    const f32x16 zero = {};

#pragma unroll 2
    for (int i2 = 0; i2 < 8; ++i2) {
        const bf16x8 b0 = *reinterpret_cast<const bf16x8*>(&bbase[(size_t)(i2 * 64) * 8]);
        const bf16x8 b1 = *reinterpret_cast<const bf16x8*>(&bbase[(size_t)(i2 * 64 + 32) * 8]);
        const f32x16 acc0 = __builtin_amdgcn_mfma_f32_32x32x16_bf16(afrag, b0, zero, 0, 0, 0);
        const f32x16 acc1 = __builtin_amdgcn_mfma_f32_32x32x16_bf16(afrag, b1, zero, 0, 0, 0);
#pragma unroll
        for (int r = 0; r < 16; ++r)
            fwd[r] = fminf(fwd[r], fminf(acc0[r], acc1[r]));   // v_min3_f32
    }

    // butterfly min across the 32-lane col dimension (halves hold distinct rows)
#pragma unroll
    for (int r = 0; r < 16; ++r) {
        float vv = fwd[r];
        vv = fminf(vv, __shfl_xor(vv, 1));
        vv = fminf(vv, __shfl_xor(vv, 2));
        vv = fminf(vv, __shfl_xor(vv, 4));
        vv = fminf(vv, __shfl_xor(vv, 8));
        vv = fminf(vv, __shfl_xor(vv, 16));
        fwd[r] = vv;
    }
    if (l31 == 0) {   // lanes 0 (row-half 0) and 32 (row-half 1)
        float* pf = part + ((size_t)ns * 16 + dir * 8 + b) * M
                  + mt * 128 + wave * 32 + hf * 4;
#pragma unroll
        for (int r = 0; r < 16; ++r)
            pf[(r & 3) + 8 * (r >> 2)] = fwd[r];
    }
}

__global__ __launch_bounds__(256) void chamfer_reduce(
    const float* __restrict__ part, float* __restrict__ out)
{
    const int idx = blockIdx.x * 256 + threadIdx.x;   // [0, 2*B*M)
    const int row = idx & (M - 1);
    const int db  = idx >> 12;                        // dir*8 + b

    const float* p = part + (size_t)db * M + row;
    float m0 = 3.0e38f, m1 = 3.0e38f;
#pragma unroll
    for (int ns = 0; ns < 8; ns += 2) {
        m0 = fminf(m0, p[(size_t)(ns + 0) * 16 * M]);
        m1 = fminf(m1, p[(size_t)(ns + 1) * 16 * M]);
    }
    const float v = fminf(m0, m1);

    float s = sqrtf(fmaxf(v, 0.0f)) * (1.0f / (float)(B * M));  // M==N: one scale
#pragma unroll
    for (int off = 32; off > 0; off >>= 1) s += __shfl_down(s, off);
    __shared__ float partial[4];
    if ((threadIdx.x & 63) == 0) partial[threadIdx.x >> 6] = s;
    __syncthreads();
    if (threadIdx.x == 0) {
        const float tot = partial[0] + partial[1] + partial[2] + partial[3];
        atomicAdd(&out[0], tot);
        atomicAdd(&out[1], tot);
        atomicAdd(&out[2], tot);
    }
}

extern "C" void kernel_launch(void* const* d_in, const int* in_sizes, int n_in,
                              void* d_out, int out_size, void* d_ws, size_t ws_size,
                              hipStream_t stream)
{
    const float* src = (const float*)d_in[0];   // [B,3,M]
    const float* dst = (const float*)d_in[1];   // [B,3,N]
    float* out = (float*)d_out;                 // 3 floats

    unsigned short* Aaug = (unsigned short*)d_ws;                     // 2 MB
    unsigned short* Baug = (unsigned short*)((char*)d_ws + (2u<<20)); // 2 MB
    float* part = (float*)((char*)d_ws + (4u << 20));                 // 2 MB

    hipMemsetAsync(d_out, 0, (size_t)out_size * sizeof(float), stream);

    chamfer_pre   <<<2 * B * M / 256, 256, 0, stream>>>(src, dst, Aaug, Baug);
    chamfer_main  <<<2 * B * 32 * 8, 256, 0, stream>>>(Aaug, Baug, part);
    chamfer_reduce<<<2 * B * M / 256, 256, 0, stream>>>(part, out);
}

// Round 9
// 31.132 us; speedup vs baseline: 1.7128x; 1.7128x over previous
//
#include <hip/hip_runtime.h>
#include <math.h>

// Chamfer loss, B=8, C=3, M=N=4096, fp32 — fused MFMA kernel, ZERO memsets.
//
// Round-9 experiment: rounds 2-8 profiles show the 12-byte hipMemsetAsync(d_out)
// as a ~40 us fillBufferAligned in the timed region (WRITE_SIZE=0.031 KB,
// dur 39-41 us) — the suspected floor. This round removes ALL memsets:
// blocks plain-store partial sums to ws; a final 1-block kernel plain-stores
// out[0..2]. Kernel body is round-7's (proven correct, absmax ~0).
//
// sq[m][n] = s2[m] + d2[n] - 2 s.d as a K=16 bf16 GEMM with hi/lo split:
//   A_m = [-2xh,-2xh,-2xl,-2xl | y.. | z.. | s2h,s2l,1,1]   (query rows)
//   B_n = [ xh,  xl,  xh,  xl  | y.. | z.. | 1,1,d2h,d2l]   (reference cols)
// C layout (m74/m101): col = lane&31, row = (reg&3) + 8*(reg>>2) + 4*(lane>>5)

constexpr int B = 8;
constexpr int M = 4096;   // == N

typedef __attribute__((ext_vector_type(8)))  short bf16x8;
typedef __attribute__((ext_vector_type(16))) float f32x16;

__device__ inline unsigned short bf16_of(float x) {   // round-to-nearest-even
    unsigned int u = __float_as_uint(x);
    u += 0x7FFFu + ((u >> 16) & 1u);
    return (unsigned short)(u >> 16);
}
__device__ inline float bf16_to_f(unsigned short h) {
    return __uint_as_float(((unsigned int)h) << 16);
}

// grid 256 = (dir<<7 | b<<4 | rg); 512 threads = 8 waves; wave w: rows rg*256+w*32..+32
__global__ __launch_bounds__(512) void chamfer_fused(
    const float* __restrict__ src,
    const float* __restrict__ dst,
    float* __restrict__ wssum)          // [256] unscaled block sums
{
    int bid = blockIdx.x;
    const int rg  = bid & 15; bid >>= 4;
    const int b   = bid & 7;  bid >>= 3;
    const int dir = bid;      // 0: rows=src, scan dst ; 1: rows=dst, scan src

    const float* __restrict__ qry = dir ? dst : src;   // A-side (rows)
    const float* __restrict__ ref = dir ? src : dst;   // B-side (cols)

    const int tid  = threadIdx.x;
    const int wave = tid >> 6;
    const int l31  = tid & 31;
    const int hf   = (tid >> 5) & 1;    // k-group / row-half within wave

    __shared__ __align__(16) unsigned short bstage[2][512][8];  // 16 KB
    __shared__ float bsum[16];

    // ---- augmented A fragment for this lane's row (constant across scan) ----
    bf16x8 afrag;
    {
        const int mrow = rg * 256 + wave * 32 + l31;
        const float* qb = qry + (size_t)b * 3 * M;
        const float x = qb[0 * M + mrow];
        const float y = qb[1 * M + mrow];
        const float z = qb[2 * M + mrow];
        const float s2 = x * x + y * y + z * z;
        const float xhf = bf16_to_f(bf16_of(x));
        const float yhf = bf16_to_f(bf16_of(y));
        const float zhf = bf16_to_f(bf16_of(z));
        // -2*hi exact (pow2 scale of a bf16 value)
        const unsigned short nxh = bf16_of(-2.0f * xhf), nxl = bf16_of(-2.0f * (x - xhf));
        const unsigned short nyh = bf16_of(-2.0f * yhf), nyl = bf16_of(-2.0f * (y - yhf));
        const unsigned short nzh = bf16_of(-2.0f * zhf), nzl = bf16_of(-2.0f * (z - zhf));
        const unsigned short s2h = bf16_of(s2);
        const unsigned short s2l = bf16_of(s2 - bf16_to_f(s2h));
        const unsigned short one = 0x3F80;
        bf16x8 alo, ahi;
        alo[0]=(short)nxh; alo[1]=(short)nxh; alo[2]=(short)nxl; alo[3]=(short)nxl;
        alo[4]=(short)nyh; alo[5]=(short)nyh; alo[6]=(short)nyl; alo[7]=(short)nyl;
        ahi[0]=(short)nzh; ahi[1]=(short)nzh; ahi[2]=(short)nzl; ahi[3]=(short)nzl;
        ahi[4]=(short)s2h; ahi[5]=(short)s2l; ahi[6]=(short)one; ahi[7]=(short)one;
        afrag = hf ? ahi : alo;
    }

    f32x16 fwd;
#pragma unroll
    for (int r = 0; r < 16; ++r) fwd[r] = 3.0e38f;

    const f32x16 zero = {};
    const float* rb = ref + (size_t)b * 3 * M;

    for (int ch = 0; ch < 8; ++ch) {
        __syncthreads();   // previous chunk fully consumed before overwrite
        {
            // stage 512 augmented B cols, one per thread (coalesced x/y/z loads)
            const int col = ch * 512 + tid;
            const float x = rb[0 * M + col];
            const float y = rb[1 * M + col];
            const float z = rb[2 * M + col];
            const float d2 = x * x + y * y + z * z;
            const unsigned short xh = bf16_of(x), xl = bf16_of(x - bf16_to_f(xh));
            const unsigned short yh = bf16_of(y), yl = bf16_of(y - bf16_to_f(yh));
            const unsigned short zh = bf16_of(z), zl = bf16_of(z - bf16_to_f(zh));
            const unsigned short d2h = bf16_of(d2);
            const unsigned short d2l = bf16_of(d2 - bf16_to_f(d2h));
            const unsigned short one = 0x3F80;
            bf16x8 v0, v1;
            v0[0]=(short)xh; v0[1]=(short)xl; v0[2]=(short)xh; v0[3]=(short)xl;
            v0[4]=(short)yh; v0[5]=(short)yl; v0[6]=(short)yh; v0[7]=(short)yl;
            v1[0]=(short)zh; v1[1]=(short)zl; v1[2]=(short)zh; v1[3]=(short)zl;
            v1[4]=(short)one; v1[5]=(short)one; v1[6]=(short)d2h; v1[7]=(short)d2l;
            *reinterpret_cast<bf16x8*>(&bstage[0][tid][0]) = v0;
            *reinterpret_cast<bf16x8*>(&bstage[1][tid][0]) = v1;
        }
        __syncthreads();

        // 16 tiles, 2 per step: per step 2 ds_read_b128 + 2 MFMA + 16 v_min3
#pragma unroll
        for (int i = 0; i < 8; ++i) {
            const bf16x8 bf0 = *reinterpret_cast<const bf16x8*>(&bstage[hf][i * 64 + l31][0]);
            const bf16x8 bf1 = *reinterpret_cast<const bf16x8*>(&bstage[hf][i * 64 + 32 + l31][0]);
            const f32x16 acc0 = __builtin_amdgcn_mfma_f32_32x32x16_bf16(afrag, bf0, zero, 0, 0, 0);
            const f32x16 acc1 = __builtin_amdgcn_mfma_f32_32x32x16_bf16(afrag, bf1, zero, 0, 0, 0);
#pragma unroll
            for (int r = 0; r < 16; ++r)
                fwd[r] = fminf(fwd[r], fminf(acc0[r], acc1[r]));   // v_min3_f32
        }
    }

    // butterfly min across the 32-lane col dimension (two halves = distinct rows)
#pragma unroll
    for (int r = 0; r < 16; ++r) {
        float vv = fwd[r];
        vv = fminf(vv, __shfl_xor(vv, 1));
        vv = fminf(vv, __shfl_xor(vv, 2));
        vv = fminf(vv, __shfl_xor(vv, 4));
        vv = fminf(vv, __shfl_xor(vv, 8));
        vv = fminf(vv, __shfl_xor(vv, 16));
        fwd[r] = vv;
    }

    // lanes with l31==0 (one per half-wave) hold 16 complete row-mins each
    if (l31 == 0) {
        float s = 0.0f;
#pragma unroll
        for (int r = 0; r < 16; ++r) s += sqrtf(fmaxf(fwd[r], 0.0f));
        bsum[wave * 2 + hf] = s;
    }
    __syncthreads();
    if (tid == 0) {
        float t = 0.0f;
#pragma unroll
        for (int i = 0; i < 16; ++i) t += bsum[i];
        wssum[blockIdx.x] = t;            // plain store, no init required
    }
}

// one block, 256 threads: sum the 256 block sums, scale, plain-store out[0..2]
__global__ __launch_bounds__(256) void chamfer_final(
    const float* __restrict__ wssum, float* __restrict__ out)
{
    float s = wssum[threadIdx.x];
#pragma unroll
    for (int off = 32; off > 0; off >>= 1) s += __shfl_down(s, off);
    __shared__ float partial[4];
    if ((threadIdx.x & 63) == 0) partial[threadIdx.x >> 6] = s;
    __syncthreads();
    if (threadIdx.x == 0) {
        const float tot = (partial[0] + partial[1] + partial[2] + partial[3])
                        * (1.0f / (float)(B * M));   // fwd /(B*M), bwd /(B*N), M==N
        out[0] = tot;
        out[1] = tot;
        out[2] = tot;
    }
}

extern "C" void kernel_launch(void* const* d_in, const int* in_sizes, int n_in,
                              void* d_out, int out_size, void* d_ws, size_t ws_size,
                              hipStream_t stream)
{
    const float* src = (const float*)d_in[0];   // [B,3,M]
    const float* dst = (const float*)d_in[1];   // [B,3,N]
    float* out = (float*)d_out;                 // 3 floats
    float* wssum = (float*)d_ws;                // 256 floats, all written each call

    chamfer_fused<<<2 * B * 16, 512, 0, stream>>>(src, dst, wssum);
    chamfer_final<<<1, 256, 0, stream>>>(wssum, out);
}

// Round 10
// 23.010 us; speedup vs baseline: 2.3174x; 1.3529x over previous
//
#include <hip/hip_runtime.h>
#include <math.h>

// Chamfer loss, B=8, C=3, M=N=4096, fp32 — MFMA, latency-hiding round.
//
// sq[m][n] = s2[m] + d2[n] - 2 s.d as a K=16 bf16 GEMM with hi/lo split:
//   A_m = [-2xh,-2xh,-2xl,-2xl | y.. | z.. | s2h,s2l,1,1]   (query rows)
//   B_n = [ xh,  xl,  xh,  xl  | y.. | z.. | 1,1,d2h,d2l]   (reference cols)
// C layout (m74/m101): col = lane&31, row = (reg&3) + 8*(reg>>2) + 4*(lane>>5)
//
// Round-10: round-9 proved the kernel is latency-bound at 2 waves/SIMD
// (~244 cyc/tile = serial ds_read->MFMA->min3 latency). This round:
//   - col-split x2: grid 1024 x 4 waves -> 4 waves/SIMD (launch_bounds(256,4))
//   - 1024-col LDS chunks (float4 staging): 4 barriers total instead of 16
//   - split min accumulators fwdE/fwdO: independent cross-step chains
//   - partial row-mins to ws (512 KB), small reduce + final kernels
//   - ZERO memsets (round-9 lesson: a 12B graph memset cost ~11 us)

constexpr int B = 8;
constexpr int M = 4096;   // == N

typedef __attribute__((ext_vector_type(8)))  short bf16x8;
typedef __attribute__((ext_vector_type(16))) float f32x16;

__device__ inline unsigned short bf16_of(float x) {   // round-to-nearest-even
    unsigned int u = __float_as_uint(x);
    u += 0x7FFFu + ((u >> 16) & 1u);
    return (unsigned short)(u >> 16);
}
__device__ inline float bf16_to_f(unsigned short h) {
    return __uint_as_float(((unsigned int)h) << 16);
}

// ws: part [2 cs][16 db][M] f32 @ 0   (512 KB)
//     bsums [256] f32 @ 512 KB

// grid 1024 = (dir<<9 | b<<6 | rg<<1 | cs); 256 thr = 4 waves
// wave w: rows rg*128 + w*32 .. +32 ; cols cs*2048 .. +2048
__global__ __launch_bounds__(256, 4) void chamfer_main(
    const float* __restrict__ src,
    const float* __restrict__ dst,
    float* __restrict__ part)
{
    int bid = blockIdx.x;
    const int cs  = bid & 1;  bid >>= 1;
    const int rg  = bid & 31; bid >>= 5;
    const int b   = bid & 7;  bid >>= 3;
    const int dir = bid;      // 0: rows=src scan dst ; 1: rows=dst scan src

    const float* __restrict__ qry = dir ? dst : src;   // A-side (rows)
    const float* __restrict__ ref = dir ? src : dst;   // B-side (cols)

    const int tid  = threadIdx.x;
    const int wave = tid >> 6;
    const int l31  = tid & 31;
    const int hf   = (tid >> 5) & 1;    // k-group / row-half within wave

    __shared__ __align__(16) unsigned short bstage[2][1024][8];  // 32 KB
    __shared__ float bsum[8];   // unused here; kept out — see epilogue store

    // ---- augmented A fragment for this lane's row (constant across scan) ----
    bf16x8 afrag;
    {
        const int mrow = rg * 128 + wave * 32 + l31;
        const float* qb = qry + (size_t)b * 3 * M;
        const float x = qb[0 * M + mrow];
        const float y = qb[1 * M + mrow];
        const float z = qb[2 * M + mrow];
        const float s2 = x * x + y * y + z * z;
        const float xhf = bf16_to_f(bf16_of(x));
        const float yhf = bf16_to_f(bf16_of(y));
        const float zhf = bf16_to_f(bf16_of(z));
        // -2*hi exact (pow2 scale of a bf16 value)
        const unsigned short nxh = bf16_of(-2.0f * xhf), nxl = bf16_of(-2.0f * (x - xhf));
        const unsigned short nyh = bf16_of(-2.0f * yhf), nyl = bf16_of(-2.0f * (y - yhf));
        const unsigned short nzh = bf16_of(-2.0f * zhf), nzl = bf16_of(-2.0f * (z - zhf));
        const unsigned short s2h = bf16_of(s2);
        const unsigned short s2l = bf16_of(s2 - bf16_to_f(s2h));
        const unsigned short one = 0x3F80;
        bf16x8 alo, ahi;
        alo[0]=(short)nxh; alo[1]=(short)nxh; alo[2]=(short)nxl; alo[3]=(short)nxl;
        alo[4]=(short)nyh; alo[5]=(short)nyh; alo[6]=(short)nyl; alo[7]=(short)nyl;
        ahi[0]=(short)nzh; ahi[1]=(short)nzh; ahi[2]=(short)nzl; ahi[3]=(short)nzl;
        ahi[4]=(short)s2h; ahi[5]=(short)s2l; ahi[6]=(short)one; ahi[7]=(short)one;
        afrag = hf ? ahi : alo;
    }

    f32x16 fwdE, fwdO;
#pragma unroll
    for (int r = 0; r < 16; ++r) { fwdE[r] = 3.0e38f; fwdO[r] = 3.0e38f; }

    const f32x16 zero = {};
    const float* rb = ref + (size_t)b * 3 * M + cs * 2048;

    for (int ch = 0; ch < 2; ++ch) {
        __syncthreads();   // previous chunk fully consumed before overwrite
        {
            // stage 1024 augmented B cols: 4 consecutive cols per thread,
            // float4 loads per coordinate row
            const int c0 = tid * 4;      // within-chunk col base
            const float4 vx = *reinterpret_cast<const float4*>(&rb[0 * M + ch * 1024 + c0]);
            const float4 vy = *reinterpret_cast<const float4*>(&rb[1 * M + ch * 1024 + c0]);
            const float4 vz = *reinterpret_cast<const float4*>(&rb[2 * M + ch * 1024 + c0]);
            const float xs[4] = {vx.x, vx.y, vx.z, vx.w};
            const float ys[4] = {vy.x, vy.y, vy.z, vy.w};
            const float zs[4] = {vz.x, vz.y, vz.z, vz.w};
#pragma unroll
            for (int k = 0; k < 4; ++k) {
                const float x = xs[k], y = ys[k], z = zs[k];
                const float d2 = x * x + y * y + z * z;
                const unsigned short xh = bf16_of(x), xl = bf16_of(x - bf16_to_f(xh));
                const unsigned short yh = bf16_of(y), yl = bf16_of(y - bf16_to_f(yh));
                const unsigned short zh = bf16_of(z), zl = bf16_of(z - bf16_to_f(zh));
                const unsigned short d2h = bf16_of(d2);
                const unsigned short d2l = bf16_of(d2 - bf16_to_f(d2h));
                const unsigned short one = 0x3F80;
                bf16x8 v0, v1;
                v0[0]=(short)xh; v0[1]=(short)xl; v0[2]=(short)xh; v0[3]=(short)xl;
                v0[4]=(short)yh; v0[5]=(short)yl; v0[6]=(short)yh; v0[7]=(short)yl;
                v1[0]=(short)zh; v1[1]=(short)zl; v1[2]=(short)zh; v1[3]=(short)zl;
                v1[4]=(short)one; v1[5]=(short)one; v1[6]=(short)d2h; v1[7]=(short)d2l;
                *reinterpret_cast<bf16x8*>(&bstage[0][c0 + k][0]) = v0;
                *reinterpret_cast<bf16x8*>(&bstage[1][c0 + k][0]) = v1;
            }
        }
        __syncthreads();

        // 32 tiles, 2 per step: 2 ds_read_b128 + 2 MFMA + 32 v_min3 (E/O split)
#pragma unroll 4
        for (int i = 0; i < 16; ++i) {
            const bf16x8 bf0 = *reinterpret_cast<const bf16x8*>(&bstage[hf][i * 64 + l31][0]);
            const bf16x8 bf1 = *reinterpret_cast<const bf16x8*>(&bstage[hf][i * 64 + 32 + l31][0]);
            const f32x16 acc0 = __builtin_amdgcn_mfma_f32_32x32x16_bf16(afrag, bf0, zero, 0, 0, 0);
            const f32x16 acc1 = __builtin_amdgcn_mfma_f32_32x32x16_bf16(afrag, bf1, zero, 0, 0, 0);
#pragma unroll
            for (int r = 0; r < 16; ++r) {
                fwdE[r] = fminf(fwdE[r], acc0[r]);
                fwdO[r] = fminf(fwdO[r], acc1[r]);
            }
        }
    }

    f32x16 fwd;
#pragma unroll
    for (int r = 0; r < 16; ++r) fwd[r] = fminf(fwdE[r], fwdO[r]);

    // butterfly min across the 32-lane col dimension (halves = distinct rows)
#pragma unroll
    for (int r = 0; r < 16; ++r) {
        float vv = fwd[r];
        vv = fminf(vv, __shfl_xor(vv, 1));
        vv = fminf(vv, __shfl_xor(vv, 2));
        vv = fminf(vv, __shfl_xor(vv, 4));
        vv = fminf(vv, __shfl_xor(vv, 8));
        vv = fminf(vv, __shfl_xor(vv, 16));
        fwd[r] = vv;
    }
    if (l31 == 0) {   // lanes 0 (row-half 0) and 32 (row-half 1): 16 row-mins each
        float* pf = part + ((size_t)cs * 16 + dir * 8 + b) * M
                  + rg * 128 + wave * 32 + hf * 4;
#pragma unroll
        for (int r = 0; r < 16; ++r)
            pf[(r & 3) + 8 * (r >> 2)] = fwd[r];
    }
    (void)bsum;
}

// 256 blocks x 256 threads: min over the 2 col-splits, sqrt, block-sum -> bsums
__global__ __launch_bounds__(256) void chamfer_reduce(
    const float* __restrict__ part, float* __restrict__ bsums)
{
    const int idx = blockIdx.x * 256 + threadIdx.x;   // [0, 2*B*M)
    const int row = idx & (M - 1);
    const int db  = idx >> 12;                        // dir*8 + b

    const float* p = part + (size_t)db * M + row;
    const float v = fminf(p[0], p[(size_t)16 * M]);

    float s = sqrtf(fmaxf(v, 0.0f));
#pragma unroll
    for (int off = 32; off > 0; off >>= 1) s += __shfl_down(s, off);
    __shared__ float partial[4];
    if ((threadIdx.x & 63) == 0) partial[threadIdx.x >> 6] = s;
    __syncthreads();
    if (threadIdx.x == 0)
        bsums[blockIdx.x] = partial[0] + partial[1] + partial[2] + partial[3];
}

// 1 block: total, scale, plain-store out[0..2] (no memset needed anywhere)
__global__ __launch_bounds__(256) void chamfer_final(
    const float* __restrict__ bsums, float* __restrict__ out)
{
    float s = bsums[threadIdx.x];
#pragma unroll
    for (int off = 32; off > 0; off >>= 1) s += __shfl_down(s, off);
    __shared__ float partial[4];
    if ((threadIdx.x & 63) == 0) partial[threadIdx.x >> 6] = s;
    __syncthreads();
    if (threadIdx.x == 0) {
        const float tot = (partial[0] + partial[1] + partial[2] + partial[3])
                        * (1.0f / (float)(B * M));   // fwd /(B*M), bwd /(B*N), M==N
        out[0] = tot;
        out[1] = tot;
        out[2] = tot;
    }
}

extern "C" void kernel_launch(void* const* d_in, const int* in_sizes, int n_in,
                              void* d_out, int out_size, void* d_ws, size_t ws_size,
                              hipStream_t stream)
{
    const float* src = (const float*)d_in[0];   // [B,3,M]
    const float* dst = (const float*)d_in[1];   // [B,3,N]
    float* out = (float*)d_out;                 // 3 floats

    float* part  = (float*)d_ws;                          // 512 KB, fully written
    float* bsums = (float*)((char*)d_ws + (1u << 19));    // 256 floats, fully written

    chamfer_main  <<<1024, 256, 0, stream>>>(src, dst, part);
    chamfer_reduce<<<256, 256, 0, stream>>>(part, bsums);
    chamfer_final <<<1, 256, 0, stream>>>(bsums, out);
}